// Round 10
// baseline (321.684 us; speedup 1.0000x reference)
//
#include <hip/hip_runtime.h>
#include <stdint.h>

// ---------------------------------------------------------------------------
// AdjCompute R10: recompute h1 instead of storing it.
// Lessons: R3 in-loop weight loads = VALU bloat; R4 per-iter LDS+waitcnt =
// latency collapse; R7/R8 store-h1 pipeline floor ~45us/pass = 75.5MB h1
// through L2/L3 (x3 passes); R9 batch-8 loads -> VGPR 180 -> occupancy 10%
// -> worse. R10: h1 is 80 VALU + 4 MFMA per 32 pos to recompute from x
// (400KB, L2-resident) -> drop bufA, fuse adj->h1 into every consumer.
//
// Pipeline (6 launches):
//   k_prep    zero stats (768 floats)
//   k_statsA  adj->h1 (MFMA 32x32x16 x4, K=64) -> stats1 moments. No writes.
//   k_statsB  adj->h1 -> act1 -> W2 -> raw2 moments (d2 excl b2). No writes.
//   k_fuseC   adj->h1 -> act1 -> W2 -> act2 -> W3 -> h3=d3+b3
//             -> bufB (37.7MB) + stats3.
//   k_stats4  VALU: h3 -> act3 -> h4 -> stats4. No writes.
//   k_last    VALU: h3 -> act3 -> h4 -> act4 -> out (fp32, 9.4MB).
//
// ws layout (floats), stats 8-replica:
//   [0..256)    stats1  8 x (sum16|ssq16)   stride 32
//   [256..512)  raw2    8 x (S16|Q16)       stride 32
//   [512..640)  stats3  8 x (sum8|ssq8)     stride 16
//   [640..768)  stats4  8 x (sum8|ssq8)     stride 16
//   byte 8192:  bufB h3: NN*8 bf16 = 37,748,736 B
//
// MFMA 32x32x16 layout (HW-verified R4/R7):
//   A[i=lane&31][k=(lane>>5)*8+j], B[k=(lane>>5)*8+j][col=lane&31],
//   D: col=lane&31, row=(reg&3)+8*(reg>>2)+4*(lane>>5).
// Stage-1: A=W1 (rows o<16 real), B=adj -> chained over 4 k-steps (K=64).
// Lane's real D regs 0..7: channel map c_r=(r&3)+8*(r>>2)+4*kh.
// act->B-frag exchange: xor-32 shfl, identical to R7/R8-verified fuse3.
// ---------------------------------------------------------------------------

#define NPTS 1536
#define NN   2359296u
static constexpr float FNN   = 2359296.0f;
static constexpr float EPS   = 1e-5f;
static constexpr float SLOPE = 0.01f;
static constexpr float INV_M = 1.0f / 2359296.0f;

typedef __attribute__((ext_vector_type(8)))  short bf16x8;
typedef __attribute__((ext_vector_type(16))) float f32x16;
union frag8 { int4 i; bf16x8 v; };

__device__ __forceinline__ float bflo(unsigned u) {
    return __builtin_bit_cast(float, u << 16);
}
__device__ __forceinline__ float bfhi(unsigned u) {
    return __builtin_bit_cast(float, u & 0xffff0000u);
}
__device__ __forceinline__ unsigned short f2bf(float f) {   // RNE
    unsigned u = __builtin_bit_cast(unsigned, f);
    u += 0x7fffu + ((u >> 16) & 1u);
    return (unsigned short)(u >> 16);
}
__device__ __forceinline__ unsigned pack2(float lo, float hi) {  // RNE pair
    return (unsigned)f2bf(lo) | ((unsigned)f2bf(hi) << 16);
}
__device__ __forceinline__ unsigned packtr(float lo, float hi) { // trunc pair
    unsigned a = __builtin_bit_cast(unsigned, lo);
    unsigned b = __builtin_bit_cast(unsigned, hi);
#if __has_builtin(__builtin_amdgcn_perm)
    return __builtin_amdgcn_perm(b, a, 0x07060302u);
#else
    return (a >> 16) | (b & 0xffff0000u);
#endif
}
__device__ __forceinline__ float lrelu(float t) {
    return fmaxf(t, t * SLOPE);
}
__device__ __forceinline__ float4 ld4(const float* p) {
    return *(const float4*)p;
}
__device__ __forceinline__ unsigned shflx32(unsigned v) {
    return (unsigned)__shfl_xor((int)v, 32);
}

// bn over 8 channels from 8-replica 8ch stats (replica stride 16)
__device__ __forceinline__ void bn8_inline(
        const float* __restrict__ stats, const float* __restrict__ g,
        const float* __restrict__ be, float* sc, float* sh) {
#pragma unroll
    for (int c = 0; c < 8; c++) {
        float S = 0.f, Q = 0.f;
#pragma unroll
        for (int r = 0; r < 8; r++) {
            S += stats[r * 16 + c];
            Q += stats[r * 16 + 8 + c];
        }
        float mu  = S * INV_M;
        float var = fmaf(-mu, mu, Q * INV_M);
        float s   = g[c] * rsqrtf(var + EPS);
        sc[c] = s;
        sh[c] = fmaf(-mu, s, be[c]);
    }
}

// --------------------------------------------------------------------------
__global__ __launch_bounds__(256) void k_prep(float* __restrict__ ws) {
    int t = blockIdx.x * 256 + threadIdx.x;
    if (t < 768) ws[t] = 0.0f;
}

// ==========================================================================
// Shared adj->h1 staging (statsA/statsB/fuseC):
// wave unit = 32 m-positions (mt) x 1 n; 8 n per wave; grid 2304x4 waves.
// Lane: pos pc = lane&31, channel-half kh = lane>>5 (8 ch per k-step).
// xm[8] float4 = lane's x row slice (32 floats); fw1[4] = W1 A-frags.
// ==========================================================================

#define ADJ_SETUP()                                                         \
    int tid  = threadIdx.x;                                                 \
    int lane = tid & 63;                                                    \
    int wv   = tid >> 6;                                                    \
    int pc   = lane & 31;                                                   \
    int kh   = lane >> 5;                                                   \
    int gid  = blockIdx.x * 4 + wv;                                         \
    int mt   = gid % 48;                                                    \
    int nch  = gid / 48;                                                    \
    int cb   = kh * 8;                                                      \
    const float* xmr = x + (size_t)(mt * 32 + pc) * 64 + cb;                \
    float4 xm[8];                                                           \
    _Pragma("unroll")                                                       \
    for (int s = 0; s < 4; s++) {                                           \
        xm[2*s]   = ld4(xmr + s * 16);                                      \
        xm[2*s+1] = ld4(xmr + s * 16 + 4);                                  \
    }                                                                       \
    frag8 fw1[4];                                                           \
    _Pragma("unroll")                                                       \
    for (int s = 0; s < 4; s++) {                                           \
        fw1[s].i = make_int4(0, 0, 0, 0);                                   \
        if (pc < 16) {                                                      \
            const float* w = W1 + pc * 64 + s * 16 + cb;                    \
            float4 a = ld4(w), b = ld4(w + 4);                              \
            fw1[s].i = make_int4(pack2(a.x, a.y), pack2(a.z, a.w),          \
                                 pack2(b.x, b.y), pack2(b.z, b.w));         \
        }                                                                   \
    }

#define ADJ_D1(n, d1)                                                       \
    {                                                                       \
        const float* xn = x + (size_t)(n) * 64 + cb;                        \
        f32x16 acc;                                                         \
        _Pragma("unroll")                                                   \
        for (int r = 0; r < 16; r++) acc[r] = 0.0f;                         \
        _Pragma("unroll")                                                   \
        for (int s = 0; s < 4; s++) {                                       \
            float4 u0 = ld4(xn + s * 16);                                   \
            float4 u1 = ld4(xn + s * 16 + 4);                               \
            float4 a0 = xm[2*s], a1 = xm[2*s+1];                            \
            frag8 fb;                                                       \
            fb.i = make_int4(                                               \
                packtr(fabsf(a0.x - u0.x), fabsf(a0.y - u0.y)),             \
                packtr(fabsf(a0.z - u0.z), fabsf(a0.w - u0.w)),             \
                packtr(fabsf(a1.x - u1.x), fabsf(a1.y - u1.y)),             \
                packtr(fabsf(a1.z - u1.z), fabsf(a1.w - u1.w)));            \
            acc = __builtin_amdgcn_mfma_f32_32x32x16_bf16(fw1[s].v, fb.v,   \
                                                          acc, 0, 0, 0);    \
        }                                                                   \
        d1 = acc;                                                           \
    }

// --------------------------------------------------------------------------
// statsA: moments of h1 = d1 + b1 (16 channels). No writes.
__global__ __launch_bounds__(256) void k_statsA(
        const float* __restrict__ x, const float* __restrict__ W1,
        const float* __restrict__ b1, float* __restrict__ stats1) {
    ADJ_SETUP();
    float b1r[8];
#pragma unroll
    for (int r = 0; r < 8; r++)
        b1r[r] = b1[(r & 3) + 8 * (r >> 2) + 4 * kh];

    float sum[8], ssq[8];
#pragma unroll
    for (int r = 0; r < 8; r++) { sum[r] = 0.f; ssq[r] = 0.f; }

#pragma unroll 1
    for (int i = 0; i < 8; i++) {
        int n = nch * 8 + i;
        f32x16 d1;
        ADJ_D1(n, d1);
#pragma unroll
        for (int r = 0; r < 8; r++) {
            float h = d1[r] + b1r[r];
            sum[r] += h;
            ssq[r] = fmaf(h, h, ssq[r]);
        }
    }
#pragma unroll
    for (int off = 1; off < 32; off <<= 1) {
#pragma unroll
        for (int r = 0; r < 8; r++) {
            sum[r] += __shfl_xor(sum[r], off);
            ssq[r] += __shfl_xor(ssq[r], off);
        }
    }
    __shared__ float red[4][32];
    if (pc == 0) {
#pragma unroll
        for (int r = 0; r < 8; r++) {
            int o = (r & 3) + 8 * (r >> 2) + 4 * kh;
            red[wv][o]      = sum[r];
            red[wv][16 + o] = ssq[r];
        }
    }
    __syncthreads();
    if (tid < 32) {
        float v = red[0][tid] + red[1][tid] + red[2][tid] + red[3][tid];
        atomicAdd(stats1 + (blockIdx.x & 7) * 32 + tid, v);
    }
}

// --------------------------------------------------------------------------
// statsB: adj->h1 -> act1 (bn1, b1 folded) -> d2 = W2*act1 -> raw2 moments.
__global__ __launch_bounds__(256) void k_statsB(
        const float* __restrict__ x, const float* __restrict__ W1,
        const float* __restrict__ b1, const float* __restrict__ stats1,
        const float* __restrict__ g1, const float* __restrict__ be1,
        const float* __restrict__ W2, float* __restrict__ raw2) {
    ADJ_SETUP();
    // bn1 for lane's 8 channels c_r (b1 folded into shift)
    float sc1r[8], shb1[8];
#pragma unroll
    for (int r = 0; r < 8; r++) {
        int c = (r & 3) + 8 * (r >> 2) + 4 * kh;
        float S = 0.f, Q = 0.f;
#pragma unroll
        for (int q = 0; q < 8; q++) {
            S += stats1[q * 32 + c];
            Q += stats1[q * 32 + 16 + c];
        }
        float mu  = S * INV_M;
        float var = fmaf(-mu, mu, Q * INV_M);
        float s   = g1[c] * rsqrtf(var + EPS);
        float sh  = fmaf(-mu, s, be1[c]);
        sc1r[r] = s;
        shb1[r] = fmaf(s, b1[c], sh);
    }
    frag8 fw2; fw2.i = make_int4(0, 0, 0, 0);
    if (pc < 16) {
        const float* w = W2 + pc * 16 + cb;
        float4 a = ld4(w), b = ld4(w + 4);
        fw2.i = make_int4(pack2(a.x, a.y), pack2(a.z, a.w),
                          pack2(b.x, b.y), pack2(b.z, b.w));
    }
    f32x16 z;
#pragma unroll
    for (int r = 0; r < 16; r++) z[r] = 0.0f;

    float sum[8], ssq[8];
#pragma unroll
    for (int r = 0; r < 8; r++) { sum[r] = 0.f; ssq[r] = 0.f; }

#pragma unroll 1
    for (int i = 0; i < 8; i++) {
        int n = nch * 8 + i;
        f32x16 d1;
        ADJ_D1(n, d1);
        float t[8];
#pragma unroll
        for (int r = 0; r < 8; r++)
            t[r] = lrelu(fmaf(d1[r], sc1r[r], shb1[r]));
        unsigned w0 = packtr(t[0], t[1]), w1 = packtr(t[2], t[3]);
        unsigned w2 = packtr(t[4], t[5]), w3 = packtr(t[6], t[7]);
        unsigned p0 = kh ? w0 : w2;
        unsigned p1 = kh ? w1 : w3;
        unsigned q0 = shflx32(p0);
        unsigned q1 = shflx32(p1);
        frag8 fb2;
        fb2.i = make_int4(kh ? q0 : w0, kh ? q1 : w1,
                          kh ? w2 : q0, kh ? w3 : q1);
        f32x16 d2 = __builtin_amdgcn_mfma_f32_32x32x16_bf16(fw2.v, fb2.v, z,
                                                            0, 0, 0);
#pragma unroll
        for (int r = 0; r < 8; r++) {
            sum[r] += d2[r];
            ssq[r] = fmaf(d2[r], d2[r], ssq[r]);
        }
    }
#pragma unroll
    for (int off = 1; off < 32; off <<= 1) {
#pragma unroll
        for (int r = 0; r < 8; r++) {
            sum[r] += __shfl_xor(sum[r], off);
            ssq[r] += __shfl_xor(ssq[r], off);
        }
    }
    __shared__ float red[4][32];
    if (pc == 0) {
#pragma unroll
        for (int r = 0; r < 8; r++) {
            int o = (r & 3) + 8 * (r >> 2) + 4 * kh;
            red[wv][o]      = sum[r];
            red[wv][16 + o] = ssq[r];
        }
    }
    __syncthreads();
    if (tid < 32) {
        float v = red[0][tid] + red[1][tid] + red[2][tid] + red[3][tid];
        atomicAdd(raw2 + (blockIdx.x & 7) * 32 + tid, v);
    }
}

// --------------------------------------------------------------------------
// fuseC: adj->h1 -> act1 -> d2 -> act2 (bn2, b2 folded) -> d3 = W3*act2
// -> h3 = d3 + b3 -> bufB + stats3.
__global__ __launch_bounds__(256) void k_fuseC(
        const float* __restrict__ x, const float* __restrict__ W1,
        const float* __restrict__ b1, const float* __restrict__ stats1,
        const float* __restrict__ g1, const float* __restrict__ be1,
        const float* __restrict__ W2, const float* __restrict__ raw2,
        const float* __restrict__ g2, const float* __restrict__ be2,
        const float* __restrict__ b2, const float* __restrict__ W3,
        const float* __restrict__ b3, unsigned short* __restrict__ h3out,
        float* __restrict__ stats3) {
    ADJ_SETUP();
    float sc1r[8], shb1[8];
#pragma unroll
    for (int r = 0; r < 8; r++) {
        int c = (r & 3) + 8 * (r >> 2) + 4 * kh;
        float S = 0.f, Q = 0.f;
#pragma unroll
        for (int q = 0; q < 8; q++) {
            S += stats1[q * 32 + c];
            Q += stats1[q * 32 + 16 + c];
        }
        float mu  = S * INV_M;
        float var = fmaf(-mu, mu, Q * INV_M);
        float s   = g1[c] * rsqrtf(var + EPS);
        float sh  = fmaf(-mu, s, be1[c]);
        sc1r[r] = s;
        shb1[r] = fmaf(s, b1[c], sh);
    }
    float sc2r[8], sh2r[8];
#pragma unroll
    for (int r = 0; r < 8; r++) {
        int c = (r & 3) + 8 * (r >> 2) + 4 * kh;
        float S = 0.f, Q = 0.f;
#pragma unroll
        for (int q = 0; q < 8; q++) {
            S += raw2[q * 32 + c];
            Q += raw2[q * 32 + 16 + c];
        }
        float bc = b2[c];
        float sm = S + FNN * bc;
        float sq = Q + 2.0f * bc * S + FNN * bc * bc;
        float mu  = sm * INV_M;
        float var = fmaf(-mu, mu, sq * INV_M);
        float s   = g2[c] * rsqrtf(var + EPS);
        float shv = fmaf(-mu, s, be2[c]);
        sc2r[r] = s;
        sh2r[r] = fmaf(s, bc, shv);
    }
    frag8 fw2; fw2.i = make_int4(0, 0, 0, 0);
    if (pc < 16) {
        const float* w = W2 + pc * 16 + cb;
        float4 a = ld4(w), b = ld4(w + 4);
        fw2.i = make_int4(pack2(a.x, a.y), pack2(a.z, a.w),
                          pack2(b.x, b.y), pack2(b.z, b.w));
    }
    frag8 fw3; fw3.i = make_int4(0, 0, 0, 0);
    if (pc < 8) {
        const float* w = W3 + pc * 16 + cb;
        float4 a = ld4(w), b = ld4(w + 4);
        fw3.i = make_int4(pack2(a.x, a.y), pack2(a.z, a.w),
                          pack2(b.x, b.y), pack2(b.z, b.w));
    }
    float b3r[4];
#pragma unroll
    for (int r = 0; r < 4; r++) b3r[r] = b3[(r & 3) + 4 * kh];

    f32x16 z;
#pragma unroll
    for (int r = 0; r < 16; r++) z[r] = 0.0f;

    float sum3[4] = {0.f, 0.f, 0.f, 0.f}, ssq3[4] = {0.f, 0.f, 0.f, 0.f};

#pragma unroll 1
    for (int i = 0; i < 8; i++) {
        int n = nch * 8 + i;
        f32x16 d1;
        ADJ_D1(n, d1);
        float t[8];
#pragma unroll
        for (int r = 0; r < 8; r++)
            t[r] = lrelu(fmaf(d1[r], sc1r[r], shb1[r]));
        unsigned w0 = packtr(t[0], t[1]), w1 = packtr(t[2], t[3]);
        unsigned w2 = packtr(t[4], t[5]), w3 = packtr(t[6], t[7]);
        unsigned p0 = kh ? w0 : w2;
        unsigned p1 = kh ? w1 : w3;
        unsigned q0 = shflx32(p0);
        unsigned q1 = shflx32(p1);
        frag8 fb2;
        fb2.i = make_int4(kh ? q0 : w0, kh ? q1 : w1,
                          kh ? w2 : q0, kh ? w3 : q1);
        f32x16 d2 = __builtin_amdgcn_mfma_f32_32x32x16_bf16(fw2.v, fb2.v, z,
                                                            0, 0, 0);
        float u[8];
#pragma unroll
        for (int r = 0; r < 8; r++)
            u[r] = lrelu(fmaf(d2[r], sc2r[r], sh2r[r]));
        unsigned y0 = packtr(u[0], u[1]), y1 = packtr(u[2], u[3]);
        unsigned y2 = packtr(u[4], u[5]), y3 = packtr(u[6], u[7]);
        unsigned r0 = kh ? y0 : y2;
        unsigned r1 = kh ? y1 : y3;
        unsigned s0 = shflx32(r0);
        unsigned s1 = shflx32(r1);
        frag8 fb3;
        fb3.i = make_int4(kh ? s0 : y0, kh ? s1 : y1,
                          kh ? y2 : s0, kh ? y3 : s1);
        f32x16 d3 = __builtin_amdgcn_mfma_f32_32x32x16_bf16(fw3.v, fb3.v, z,
                                                            0, 0, 0);
        float h0 = d3[0] + b3r[0];
        float h1v = d3[1] + b3r[1];
        float h2 = d3[2] + b3r[2];
        float h3v = d3[3] + b3r[3];
        sum3[0] += h0;  ssq3[0] = fmaf(h0, h0, ssq3[0]);
        sum3[1] += h1v; ssq3[1] = fmaf(h1v, h1v, ssq3[1]);
        sum3[2] += h2;  ssq3[2] = fmaf(h2, h2, ssq3[2]);
        sum3[3] += h3v; ssq3[3] = fmaf(h3v, h3v, ssq3[3]);
        size_t pos = (size_t)n * NPTS + mt * 32 + pc;
        *(uint2*)(h3out + pos * 8 + kh * 4) =
            make_uint2(pack2(h0, h1v), pack2(h2, h3v));
    }
#pragma unroll
    for (int off = 1; off < 32; off <<= 1) {
#pragma unroll
        for (int r = 0; r < 4; r++) {
            sum3[r] += __shfl_xor(sum3[r], off);
            ssq3[r] += __shfl_xor(ssq3[r], off);
        }
    }
    __shared__ float red[4][16];
    if (pc == 0) {
#pragma unroll
        for (int r = 0; r < 4; r++) {
            red[wv][kh * 4 + r]     = sum3[r];
            red[wv][8 + kh * 4 + r] = ssq3[r];
        }
    }
    __syncthreads();
    if (tid < 16) {
        float v = red[0][tid] + red[1][tid] + red[2][tid] + red[3][tid];
        atomicAdd(stats3 + (blockIdx.x & 7) * 16 + tid, v);
    }
}

// --------------------------------------------------------------------------
// stats4 (VALU, R8 shape): h3 -> act3 -> h4 = W4*act3+b4 -> stats4.
__global__ __launch_bounds__(256) void k_stats4(
        const unsigned short* __restrict__ h3,
        const float* __restrict__ stats3, const float* __restrict__ g3,
        const float* __restrict__ be3, const float* __restrict__ W4,
        const float* __restrict__ b4, float* __restrict__ stats4) {
    int tid = threadIdx.x;
    int og1 = tid & 1;

    float sc[8], sh[8];
    bn8_inline(stats3, g3, be3, sc, sh);

    float w[4][8];
#pragma unroll
    for (int j = 0; j < 4; j++) {
        const float* wr = W4 + (og1 * 4 + j) * 8;
        float4 v0 = ld4(wr);
        float4 v1 = ld4(wr + 4);
        w[j][0] = v0.x; w[j][1] = v0.y; w[j][2] = v0.z; w[j][3] = v0.w;
        w[j][4] = v1.x; w[j][5] = v1.y; w[j][6] = v1.z; w[j][7] = v1.w;
    }
    float bi[4];
#pragma unroll
    for (int j = 0; j < 4; j++) bi[j] = b4[og1 * 4 + j];

    float sum[4] = {0.f, 0.f, 0.f, 0.f}, ssq[4] = {0.f, 0.f, 0.f, 0.f};

    size_t p0 = (size_t)blockIdx.x * 1024 + (tid >> 1);
    const uint4* src = (const uint4*)h3 + p0;

    auto proc = [&](uint4 v) {
        float a[8];
        a[0] = bflo(v.x); a[1] = bfhi(v.x); a[2] = bflo(v.y); a[3] = bfhi(v.y);
        a[4] = bflo(v.z); a[5] = bfhi(v.z); a[6] = bflo(v.w); a[7] = bfhi(v.w);
#pragma unroll
        for (int c = 0; c < 8; c++)
            a[c] = lrelu(fmaf(a[c], sc[c], sh[c]));
        float d[4] = {bi[0], bi[1], bi[2], bi[3]};
#pragma unroll
        for (int c = 0; c < 8; c++) {
#pragma unroll
            for (int j = 0; j < 4; j++)
                d[j] = fmaf(a[c], w[j][c], d[j]);
        }
#pragma unroll
        for (int j = 0; j < 4; j++) {
            sum[j] += d[j];
            ssq[j] = fmaf(d[j], d[j], ssq[j]);
        }
    };

    uint4 vA = src[0];
    uint4 vB = src[128];
#pragma unroll 1
    for (int p = 0; p < 4; p++) {
        uint4 nA = vA, nB = vB;
        if (p < 3) {
            nA = src[(size_t)(2 * p + 2) * 128];
            nB = src[(size_t)(2 * p + 3) * 128];
        }
        proc(vA);
        proc(vB);
        vA = nA; vB = nB;
    }
#pragma unroll
    for (int off = 2; off < 64; off <<= 1) {
#pragma unroll
        for (int j = 0; j < 4; j++) {
            sum[j] += __shfl_xor(sum[j], off);
            ssq[j] += __shfl_xor(ssq[j], off);
        }
    }
    __shared__ float red[4][16];
    int wv = tid >> 6, lane = tid & 63;
    if (lane < 2) {
#pragma unroll
        for (int j = 0; j < 4; j++) {
            red[wv][og1 * 4 + j]     = sum[j];
            red[wv][8 + og1 * 4 + j] = ssq[j];
        }
    }
    __syncthreads();
    if (tid < 16) {
        float v = red[0][tid] + red[1][tid] + red[2][tid] + red[3][tid];
        atomicAdd(stats4 + (blockIdx.x & 7) * 16 + tid, v);
    }
}

// --------------------------------------------------------------------------
// last (VALU, R8 shape): h3 -> act3 -> h4 (bn4-folded W4) -> act4 -> out
__global__ __launch_bounds__(256) void k_last(
        const unsigned short* __restrict__ h3,
        const float* __restrict__ stats3, const float* __restrict__ g3,
        const float* __restrict__ be3, const float* __restrict__ stats4,
        const float* __restrict__ g4, const float* __restrict__ be4,
        const float* __restrict__ W4, const float* __restrict__ b4,
        const float* __restrict__ W5, const float* __restrict__ b5,
        float* __restrict__ out) {
    int tid = threadIdx.x;

    size_t p0 = (size_t)blockIdx.x * 1024 + tid;
    const uint4* src = (const uint4*)h3 + p0;
    uint4 vv[4];
    vv[0] = src[0];
    vv[1] = src[256];
    vv[2] = src[512];
    vv[3] = src[768];

    float sc3[8], sh3[8];
    bn8_inline(stats3, g3, be3, sc3, sh3);

    float w4f[8][8], b4f[8], w5[8];
#pragma unroll
    for (int o = 0; o < 8; o++) {
        float S = 0.f, Q = 0.f;
#pragma unroll
        for (int r = 0; r < 8; r++) {
            S += stats4[r * 16 + o];
            Q += stats4[r * 16 + 8 + o];
        }
        float mu  = S * INV_M;
        float var = fmaf(-mu, mu, Q * INV_M);
        float s   = g4[o] * rsqrtf(var + EPS);
        float shv = fmaf(-mu, s, be4[o]);
        b4f[o] = fmaf(s, b4[o], shv);
        const float* wr = W4 + o * 8;
        float4 v0 = ld4(wr);
        float4 v1 = ld4(wr + 4);
        w4f[o][0] = s * v0.x; w4f[o][1] = s * v0.y;
        w4f[o][2] = s * v0.z; w4f[o][3] = s * v0.w;
        w4f[o][4] = s * v1.x; w4f[o][5] = s * v1.y;
        w4f[o][6] = s * v1.z; w4f[o][7] = s * v1.w;
        w5[o] = W5[o];
    }
    float b5v = b5[0];

#pragma unroll
    for (int it = 0; it < 4; it++) {
        uint4 va = vv[it];
        float a[8];
        a[0] = bflo(va.x); a[1] = bfhi(va.x); a[2] = bflo(va.y); a[3] = bfhi(va.y);
        a[4] = bflo(va.z); a[5] = bfhi(va.z); a[6] = bflo(va.w); a[7] = bfhi(va.w);
#pragma unroll
        for (int c = 0; c < 8; c++)
            a[c] = lrelu(fmaf(a[c], sc3[c], sh3[c]));
        float acc = b5v;
#pragma unroll
        for (int o = 0; o < 8; o++) {
            float h = b4f[o];
#pragma unroll
            for (int c = 0; c < 8; c++)
                h = fmaf(a[c], w4f[o][c], h);
            acc = fmaf(lrelu(h), w5[o], acc);
        }
        out[p0 + (size_t)it * 256] = acc;
    }
}

// --------------------------------------------------------------------------
extern "C" void kernel_launch(void* const* d_in, const int* in_sizes, int n_in,
                              void* d_out, int out_size, void* d_ws,
                              size_t ws_size, hipStream_t stream) {
    const float* x   = (const float*)d_in[0];
    const float* W1  = (const float*)d_in[1];
    const float* b1  = (const float*)d_in[2];
    const float* g1  = (const float*)d_in[3];
    const float* be1 = (const float*)d_in[4];
    const float* W2  = (const float*)d_in[5];
    const float* b2  = (const float*)d_in[6];
    const float* g2  = (const float*)d_in[7];
    const float* be2 = (const float*)d_in[8];
    const float* W3  = (const float*)d_in[9];
    const float* b3  = (const float*)d_in[10];
    const float* g3  = (const float*)d_in[11];
    const float* be3 = (const float*)d_in[12];
    const float* W4  = (const float*)d_in[13];
    const float* b4  = (const float*)d_in[14];
    const float* g4  = (const float*)d_in[15];
    const float* be4 = (const float*)d_in[16];
    const float* W5  = (const float*)d_in[17];
    const float* b5  = (const float*)d_in[18];

    float* ws     = (float*)d_ws;
    float* stats1 = ws + 0;     // 8 x 32
    float* raw2   = ws + 256;   // 8 x 32
    float* stats3 = ws + 512;   // 8 x 16
    float* stats4 = ws + 640;   // 8 x 16
    unsigned short* bufB = (unsigned short*)((char*)d_ws + 8192);

    k_prep<<<3, 256, 0, stream>>>(ws);
    k_statsA<<<2304, 256, 0, stream>>>(x, W1, b1, stats1);
    k_statsB<<<2304, 256, 0, stream>>>(x, W1, b1, stats1, g1, be1, W2, raw2);
    k_fuseC<<<2304, 256, 0, stream>>>(x, W1, b1, stats1, g1, be1, W2,
                                      raw2, g2, be2, b2, W3, b3, bufB,
                                      stats3);
    k_stats4<<<2304, 256, 0, stream>>>(bufB, stats3, g3, be3, W4, b4, stats4);
    k_last<<<2304, 256, 0, stream>>>(bufB, stats3, g3, be3, stats4, g4, be4,
                                     W4, b4, W5, b5, (float*)d_out);
}

// Round 11
// 193.125 us; speedup vs baseline: 1.6657x; 1.6657x over previous
//
#include <hip/hip_runtime.h>
#include <stdint.h>

// ---------------------------------------------------------------------------
// AdjCompute R11: symmetry halving on top of R8 (best, 231.8us).
// adj[n,m]=adj[m,n] and all layers are per-position => h1/h3/out are
// SYMMETRIC. Compute only triangle tiles (mt<=nc), 4656 of 9216 16x16
// tiles; stats stay EXACT via per-tile weight (off-diag x2, diag x1;
// 2*h == h+h in fp32). h1/h3 triangle-packed; k_last mirrors the output.
// Lessons: R3 in-loop weight loads; R4 LDS+waitcnt serialization; R7-R10:
// ~40-55us per full pass regardless of memory-vs-recompute => reduce work
// per pass (this round), not its schedule.
//
// Pipeline (6 launches, grids 1164 = 4656 tiles / 4 waves):
//   k_prep    zero stats (384 floats)
//   k_layer1  MFMA 16x16x32: h1 tile -> bufA packed + stats1 (weighted)
//   k_stats2  MFMA 32x32x16: moments of d2 = W2*act1 (weighted, no write)
//   k_fuse3   MFMA 32x32x16 x2: act1 -> d2 -> act2 -> h3 -> bufB + stats3
//   k_stats4  VALU: stats of h4 (weighted, no write)
//   k_last    VALU: h3 -> out tile + mirrored tile (fp32)
//
// ws layout (floats), stats 4-replica:
//   [0..128)    stats1  4 x (sum16|ssq16)   stride 32
//   [128..256)  raw2    4 x (S16|Q16)       stride 32
//   [256..320)  stats3  4 x (sum8|ssq8)     stride 16
//   [320..384)  stats4  4 x (sum8|ssq8)     stride 16
//   byte 8192:            bufA h1: 4656*256*16 bf16 = 38,141,952 B
//   byte 8192+38141952:   bufB h3: 4656*256*8  bf16 = 19,070,976 B
//
// Tile t in [0,4656): (mt,nc), 0<=mt<=nc<96, row-major in mt.
// In-tile flat pos p = nl*16 + ml  (nl = local n, ml = local m).
// MFMA layouts (HW-verified R4/R7): see R8 header.
// ---------------------------------------------------------------------------

#define NPTS 1536
#define NTILES 4656
static constexpr float FNN   = 2359296.0f;
static constexpr float EPS   = 1e-5f;
static constexpr float SLOPE = 0.01f;
static constexpr float INV_M = 1.0f / 2359296.0f;

typedef __attribute__((ext_vector_type(8)))  short bf16x8;
typedef __attribute__((ext_vector_type(4)))  float f32x4;
typedef __attribute__((ext_vector_type(16))) float f32x16;
union frag8 { int4 i; bf16x8 v; };

__device__ __forceinline__ float bflo(unsigned u) {
    return __builtin_bit_cast(float, u << 16);
}
__device__ __forceinline__ float bfhi(unsigned u) {
    return __builtin_bit_cast(float, u & 0xffff0000u);
}
__device__ __forceinline__ unsigned short f2bf(float f) {   // RNE
    unsigned u = __builtin_bit_cast(unsigned, f);
    u += 0x7fffu + ((u >> 16) & 1u);
    return (unsigned short)(u >> 16);
}
__device__ __forceinline__ unsigned pack2(float lo, float hi) {  // RNE pair
    return (unsigned)f2bf(lo) | ((unsigned)f2bf(hi) << 16);
}
__device__ __forceinline__ unsigned packtr(float lo, float hi) { // trunc
    unsigned a = __builtin_bit_cast(unsigned, lo);
    unsigned b = __builtin_bit_cast(unsigned, hi);
#if __has_builtin(__builtin_amdgcn_perm)
    return __builtin_amdgcn_perm(b, a, 0x07060302u);
#else
    return (a >> 16) | (b & 0xffff0000u);
#endif
}
__device__ __forceinline__ float lrelu(float t) {
    return fmaxf(t, t * SLOPE);
}
__device__ __forceinline__ float4 ld4(const float* p) {
    return *(const float4*)p;
}
__device__ __forceinline__ unsigned shflx32(unsigned v) {
    return (unsigned)__shfl_xor((int)v, 32);
}

// triangle tile decode: t -> (mt, nc), 0<=mt<=nc<96, row-major in mt.
// base(mt) = 96*mt - mt*(mt-1)/2.
__device__ __forceinline__ int2 tri_decode(int t) {
    float disc = 37249.0f - 8.0f * (float)t;    // 193^2 - 8t
    int mt = (int)((193.0f - sqrtf(disc)) * 0.5f);
    if (mt < 0) mt = 0;
    if (mt > 95) mt = 95;
    while (96 * (mt + 1) - ((mt + 1) * mt) / 2 <= t) mt++;
    while (96 * mt - (mt * (mt - 1)) / 2 > t) mt--;
    int nc = mt + (t - (96 * mt - (mt * (mt - 1)) / 2));
    return make_int2(mt, nc);
}

// bn over 8 channels from 4-replica 8ch stats (replica stride 16)
__device__ __forceinline__ void bn8_inline(
        const float* __restrict__ stats, const float* __restrict__ g,
        const float* __restrict__ be, float* sc, float* sh) {
#pragma unroll
    for (int c = 0; c < 8; c++) {
        float S = stats[c] + stats[16 + c] + stats[32 + c] + stats[48 + c];
        float Q = stats[8 + c] + stats[24 + c] + stats[40 + c] +
                  stats[56 + c];
        float mu  = S * INV_M;
        float var = fmaf(-mu, mu, Q * INV_M);
        float s   = g[c] * rsqrtf(var + EPS);
        sc[c] = s;
        sh[c] = fmaf(-mu, s, be[c]);
    }
}

// --------------------------------------------------------------------------
__global__ __launch_bounds__(256) void k_prep(float* __restrict__ ws) {
    int t = blockIdx.x * 256 + threadIdx.x;
    if (t < 384) ws[t] = 0.0f;
}

// --------------------------------------------------------------------------
// Layer 1: triangle tile gid -> h1 packed + weighted stats1.
// wave = 16 m (tile mt) x 16 n (chunk nc). MFMA A=W1, B=adj -> D[o][m].
__global__ __launch_bounds__(256) void k_layer1(
        const float* __restrict__ x, const float* __restrict__ W1,
        const float* __restrict__ b1, unsigned short* __restrict__ outb,
        float* __restrict__ stats) {
    int tid  = threadIdx.x;
    int lane = tid & 63;
    int wv   = tid >> 6;
    int gid  = blockIdx.x * 4 + wv;
    int2 tc  = tri_decode(gid);
    int mt   = tc.x;
    int nc   = tc.y;
    float wf = (mt == nc) ? 1.0f : 2.0f;
    int l15  = lane & 15;
    int quad = lane >> 4;
    int cb   = quad * 8;

    const float* wr = W1 + l15 * 64 + cb;
    float4 w0 = ld4(wr);
    float4 w1 = ld4(wr + 4);
    float4 w2 = ld4(wr + 32);
    float4 w3 = ld4(wr + 36);
    frag8 fb1, fb2;
    fb1.i = make_int4(pack2(w0.x, w0.y), pack2(w0.z, w0.w),
                      pack2(w1.x, w1.y), pack2(w1.z, w1.w));
    fb2.i = make_int4(pack2(w2.x, w2.y), pack2(w2.z, w2.w),
                      pack2(w3.x, w3.y), pack2(w3.z, w3.w));

    const float* xr = x + (mt * 16 + l15) * 64 + cb;
    float4 xa0 = ld4(xr);
    float4 xa1 = ld4(xr + 4);
    float4 xa2 = ld4(xr + 32);
    float4 xa3 = ld4(xr + 36);

    float4 b1v = ld4(b1 + quad * 4);
    float lsum[4] = {0.f, 0.f, 0.f, 0.f};
    float lssq[4] = {0.f, 0.f, 0.f, 0.f};

    int n0 = nc * 16;
    const float* xp = x + (size_t)n0 * 64 + cb;
    float4 uA0 = ld4(xp);
    float4 uA1 = ld4(xp + 4);
    float4 uA2 = ld4(xp + 32);
    float4 uA3 = ld4(xp + 36);
    const float* xq = x + (size_t)(n0 + 1) * 64 + cb;
    float4 uB0 = ld4(xq);
    float4 uB1 = ld4(xq + 4);
    float4 uB2 = ld4(xq + 32);
    float4 uB3 = ld4(xq + 36);

    auto body = [&](int i, float4& u0, float4& u1, float4& u2, float4& u3,
                    int pf) {
        frag8 fa1, fa2;
        fa1.i = make_int4(
            packtr(fabsf(xa0.x - u0.x), fabsf(xa0.y - u0.y)),
            packtr(fabsf(xa0.z - u0.z), fabsf(xa0.w - u0.w)),
            packtr(fabsf(xa1.x - u1.x), fabsf(xa1.y - u1.y)),
            packtr(fabsf(xa1.z - u1.z), fabsf(xa1.w - u1.w)));
        fa2.i = make_int4(
            packtr(fabsf(xa2.x - u2.x), fabsf(xa2.y - u2.y)),
            packtr(fabsf(xa2.z - u2.z), fabsf(xa2.w - u2.w)),
            packtr(fabsf(xa3.x - u3.x), fabsf(xa3.y - u3.y)),
            packtr(fabsf(xa3.z - u3.z), fabsf(xa3.w - u3.w)));
        const float* xf = x + (size_t)pf * 64 + cb;
        u0 = ld4(xf);
        u1 = ld4(xf + 4);
        u2 = ld4(xf + 32);
        u3 = ld4(xf + 36);
        f32x4 acc = {b1v.x, b1v.y, b1v.z, b1v.w};
        acc = __builtin_amdgcn_mfma_f32_16x16x32_bf16(fb1.v, fa1.v, acc, 0, 0, 0);
        acc = __builtin_amdgcn_mfma_f32_16x16x32_bf16(fb2.v, fa2.v, acc, 0, 0, 0);
        size_t pos = (size_t)gid * 256 + (size_t)i * 16 + l15;
#pragma unroll
        for (int r = 0; r < 4; r++) {
            lsum[r] += acc[r];
            lssq[r] = fmaf(acc[r], acc[r], lssq[r]);
        }
        *(uint2*)(outb + pos * 16 + quad * 4) =
            make_uint2(pack2(acc[0], acc[1]), pack2(acc[2], acc[3]));
    };

#pragma unroll 1
    for (int i = 0; i < 16; i += 2) {
        int pfA = n0 + ((i + 2 < 16) ? i + 2 : 15);
        int pfB = n0 + ((i + 3 < 16) ? i + 3 : 15);
        body(i,     uA0, uA1, uA2, uA3, pfA);
        body(i + 1, uB0, uB1, uB2, uB3, pfB);
    }

#pragma unroll
    for (int off = 1; off < 16; off <<= 1) {
#pragma unroll
        for (int r = 0; r < 4; r++) {
            lsum[r] += __shfl_xor(lsum[r], off);
            lssq[r] += __shfl_xor(lssq[r], off);
        }
    }
    __shared__ float red[4][32];
    if (l15 == 0) {
#pragma unroll
        for (int r = 0; r < 4; r++) {
            red[wv][quad * 4 + r]      = lsum[r] * wf;
            red[wv][16 + quad * 4 + r] = lssq[r] * wf;
        }
    }
    __syncthreads();
    if (tid < 32) {
        float v = red[0][tid] + red[1][tid] + red[2][tid] + red[3][tid];
        atomicAdd(stats + (blockIdx.x & 3) * 32 + tid, v);
    }
}

// --------------------------------------------------------------------------
// stats2 (32x32x16): tile gid = 8 chunks of 32 positions; weighted moments.
__global__ __launch_bounds__(256) void k_stats2(
        const unsigned short* __restrict__ h1,
        const float* __restrict__ stats1, const float* __restrict__ g1,
        const float* __restrict__ be1, const float* __restrict__ W2,
        float* __restrict__ raw2) {
    int tid  = threadIdx.x;
    int lane = tid & 63;
    int wv   = tid >> 6;
    int pc   = lane & 31;
    int kh   = lane >> 5;
    int gid  = blockIdx.x * 4 + wv;
    int2 tc  = tri_decode(gid);
    float wf = (tc.x == tc.y) ? 1.0f : 2.0f;

    float sc[8], sh[8];
#pragma unroll
    for (int j = 0; j < 8; j++) {
        int c = kh * 8 + j;
        float S = stats1[c] + stats1[32 + c] + stats1[64 + c] + stats1[96 + c];
        float Q = stats1[16 + c] + stats1[48 + c] + stats1[80 + c] +
                  stats1[112 + c];
        float mu  = S * INV_M;
        float var = fmaf(-mu, mu, Q * INV_M);
        float s   = g1[c] * rsqrtf(var + EPS);
        sc[j] = s;
        sh[j] = fmaf(-mu, s, be1[c]);
    }
    frag8 fw2; fw2.i = make_int4(0, 0, 0, 0);
    if (pc < 16) {
        const float* w = W2 + pc * 16 + kh * 8;
        float4 wa = ld4(w), wb = ld4(w + 4);
        fw2.i = make_int4(pack2(wa.x, wa.y), pack2(wa.z, wa.w),
                          pack2(wb.x, wb.y), pack2(wb.z, wb.w));
    }
    f32x16 z;
#pragma unroll
    for (int r = 0; r < 16; r++) z[r] = 0.0f;

    float sum[8], ssq[8];
#pragma unroll
    for (int r = 0; r < 8; r++) { sum[r] = 0.f; ssq[r] = 0.f; }

    size_t tile0 = (size_t)gid * 8;
    const unsigned short* ptr = h1 + (tile0 * 32 + pc) * 16 + kh * 8;

    auto proc = [&](uint4 v) {
        float a0 = bflo(v.x), a1 = bfhi(v.x);
        float a2 = bflo(v.y), a3 = bfhi(v.y);
        float a4 = bflo(v.z), a5 = bfhi(v.z);
        float a6 = bflo(v.w), a7 = bfhi(v.w);
        a0 = lrelu(fmaf(a0, sc[0], sh[0]));
        a1 = lrelu(fmaf(a1, sc[1], sh[1]));
        a2 = lrelu(fmaf(a2, sc[2], sh[2]));
        a3 = lrelu(fmaf(a3, sc[3], sh[3]));
        a4 = lrelu(fmaf(a4, sc[4], sh[4]));
        a5 = lrelu(fmaf(a5, sc[5], sh[5]));
        a6 = lrelu(fmaf(a6, sc[6], sh[6]));
        a7 = lrelu(fmaf(a7, sc[7], sh[7]));
        frag8 fb;
        fb.i = make_int4(packtr(a0, a1), packtr(a2, a3),
                         packtr(a4, a5), packtr(a6, a7));
        f32x16 d = __builtin_amdgcn_mfma_f32_32x32x16_bf16(fw2.v, fb.v, z, 0, 0, 0);
#pragma unroll
        for (int r = 0; r < 8; r++) {
            sum[r] += d[r];
            ssq[r] = fmaf(d[r], d[r], ssq[r]);
        }
    };

    uint4 vA = *(const uint4*)(ptr);
    uint4 vB = *(const uint4*)(ptr + 512);
#pragma unroll 1
    for (int p = 0; p < 4; p++) {
        uint4 nA = vA, nB = vB;
        if (p < 3) {
            nA = *(const uint4*)(ptr + (size_t)(2 * p + 2) * 512);
            nB = *(const uint4*)(ptr + (size_t)(2 * p + 3) * 512);
        }
        proc(vA);
        proc(vB);
        vA = nA; vB = nB;
    }

#pragma unroll
    for (int off = 1; off < 32; off <<= 1) {
#pragma unroll
        for (int r = 0; r < 8; r++) {
            sum[r] += __shfl_xor(sum[r], off);
            ssq[r] += __shfl_xor(ssq[r], off);
        }
    }
    __shared__ float red[4][32];
    if (pc == 0) {
#pragma unroll
        for (int r = 0; r < 8; r++) {
            int o = (r & 3) + 8 * (r >> 2) + 4 * kh;
            red[wv][o]      = sum[r] * wf;
            red[wv][16 + o] = ssq[r] * wf;
        }
    }
    __syncthreads();
    if (tid < 32) {
        float v = red[0][tid] + red[1][tid] + red[2][tid] + red[3][tid];
        atomicAdd(raw2 + (blockIdx.x & 3) * 32 + tid, v);
    }
}

// --------------------------------------------------------------------------
// fuse3 (32x32x16 x2): tile gid; weighted stats3; h3 packed.
__global__ __launch_bounds__(256) void k_fuse3(
        const unsigned short* __restrict__ h1,
        unsigned short* __restrict__ h3out,
        const float* __restrict__ stats1, const float* __restrict__ g1,
        const float* __restrict__ be1, const float* __restrict__ W2,
        const float* __restrict__ raw2, const float* __restrict__ g2,
        const float* __restrict__ be2, const float* __restrict__ b2,
        const float* __restrict__ W3, const float* __restrict__ b3,
        float* __restrict__ stats3) {
    int tid  = threadIdx.x;
    int lane = tid & 63;
    int wv   = tid >> 6;
    int pc   = lane & 31;
    int kh   = lane >> 5;
    int gid  = blockIdx.x * 4 + wv;
    int2 tc  = tri_decode(gid);
    float wf = (tc.x == tc.y) ? 1.0f : 2.0f;

    float sc[8], sh[8];
#pragma unroll
    for (int j = 0; j < 8; j++) {
        int c = kh * 8 + j;
        float S = stats1[c] + stats1[32 + c] + stats1[64 + c] + stats1[96 + c];
        float Q = stats1[16 + c] + stats1[48 + c] + stats1[80 + c] +
                  stats1[112 + c];
        float mu  = S * INV_M;
        float var = fmaf(-mu, mu, Q * INV_M);
        float s   = g1[c] * rsqrtf(var + EPS);
        sc[j] = s;
        sh[j] = fmaf(-mu, s, be1[c]);
    }
    float sc2[8], sh2[8];
#pragma unroll
    for (int r = 0; r < 8; r++) {
        int c = (r & 3) + 8 * (r >> 2) + 4 * kh;
        float S = raw2[c] + raw2[32 + c] + raw2[64 + c] + raw2[96 + c];
        float Q = raw2[16 + c] + raw2[48 + c] + raw2[80 + c] + raw2[112 + c];
        float bc = b2[c];
        float sm = S + FNN * bc;
        float sq = Q + 2.0f * bc * S + FNN * bc * bc;
        float mu  = sm * INV_M;
        float var = fmaf(-mu, mu, sq * INV_M);
        float s   = g2[c] * rsqrtf(var + EPS);
        float shv = fmaf(-mu, s, be2[c]);
        sc2[r] = s;
        sh2[r] = fmaf(s, bc, shv);
    }
    frag8 fw2; fw2.i = make_int4(0, 0, 0, 0);
    if (pc < 16) {
        const float* w = W2 + pc * 16 + kh * 8;
        float4 wa = ld4(w), wb = ld4(w + 4);
        fw2.i = make_int4(pack2(wa.x, wa.y), pack2(wa.z, wa.w),
                          pack2(wb.x, wb.y), pack2(wb.z, wb.w));
    }
    frag8 fw3; fw3.i = make_int4(0, 0, 0, 0);
    if (pc < 8) {
        const float* w = W3 + pc * 16 + kh * 8;
        float4 wa = ld4(w), wb = ld4(w + 4);
        fw3.i = make_int4(pack2(wa.x, wa.y), pack2(wa.z, wa.w),
                          pack2(wb.x, wb.y), pack2(wb.z, wb.w));
    }
    float b3r[4];
#pragma unroll
    for (int r = 0; r < 4; r++) b3r[r] = b3[kh * 4 + r];

    f32x16 z;
#pragma unroll
    for (int r = 0; r < 16; r++) z[r] = 0.0f;

    float sum3[4] = {0.f, 0.f, 0.f, 0.f}, ssq3[4] = {0.f, 0.f, 0.f, 0.f};

    size_t tile0 = (size_t)gid * 8;
    const unsigned short* ptr = h1 + (tile0 * 32 + pc) * 16 + kh * 8;

    uint4 v0 = *(const uint4*)(ptr);
    uint4 v1 = *(const uint4*)(ptr + 512);
#pragma unroll 1
    for (int it = 0; it < 8; it++) {
        uint4 nx = v0;
        if (it + 2 < 8)
            nx = *(const uint4*)(ptr + (size_t)(it + 2) * 512);
        float a0 = bflo(v0.x), a1 = bfhi(v0.x);
        float a2 = bflo(v0.y), a3 = bfhi(v0.y);
        float a4 = bflo(v0.z), a5 = bfhi(v0.z);
        float a6 = bflo(v0.w), a7 = bfhi(v0.w);
        a0 = lrelu(fmaf(a0, sc[0], sh[0]));
        a1 = lrelu(fmaf(a1, sc[1], sh[1]));
        a2 = lrelu(fmaf(a2, sc[2], sh[2]));
        a3 = lrelu(fmaf(a3, sc[3], sh[3]));
        a4 = lrelu(fmaf(a4, sc[4], sh[4]));
        a5 = lrelu(fmaf(a5, sc[5], sh[5]));
        a6 = lrelu(fmaf(a6, sc[6], sh[6]));
        a7 = lrelu(fmaf(a7, sc[7], sh[7]));
        frag8 fb;
        fb.i = make_int4(packtr(a0, a1), packtr(a2, a3),
                         packtr(a4, a5), packtr(a6, a7));
        f32x16 d = __builtin_amdgcn_mfma_f32_32x32x16_bf16(fw2.v, fb.v, z, 0, 0, 0);
        float t0 = lrelu(fmaf(d[0], sc2[0], sh2[0]));
        float t1 = lrelu(fmaf(d[1], sc2[1], sh2[1]));
        float t2 = lrelu(fmaf(d[2], sc2[2], sh2[2]));
        float t3 = lrelu(fmaf(d[3], sc2[3], sh2[3]));
        float t4 = lrelu(fmaf(d[4], sc2[4], sh2[4]));
        float t5 = lrelu(fmaf(d[5], sc2[5], sh2[5]));
        float t6 = lrelu(fmaf(d[6], sc2[6], sh2[6]));
        float t7 = lrelu(fmaf(d[7], sc2[7], sh2[7]));
        unsigned w0 = packtr(t0, t1), w1 = packtr(t2, t3);
        unsigned w2 = packtr(t4, t5), w3 = packtr(t6, t7);
        unsigned p0 = kh ? w0 : w2;
        unsigned p1 = kh ? w1 : w3;
        unsigned q0 = shflx32(p0);
        unsigned q1 = shflx32(p1);
        frag8 fb2;
        fb2.i = make_int4(kh ? q0 : w0, kh ? q1 : w1,
                          kh ? w2 : q0, kh ? w3 : q1);
        f32x16 d2 = __builtin_amdgcn_mfma_f32_32x32x16_bf16(fw3.v, fb2.v, z, 0, 0, 0);
        float h0 = d2[0] + b3r[0];
        float h1v = d2[1] + b3r[1];
        float h2 = d2[2] + b3r[2];
        float h3v = d2[3] + b3r[3];
        sum3[0] += h0;  ssq3[0] = fmaf(h0, h0, ssq3[0]);
        sum3[1] += h1v; ssq3[1] = fmaf(h1v, h1v, ssq3[1]);
        sum3[2] += h2;  ssq3[2] = fmaf(h2, h2, ssq3[2]);
        sum3[3] += h3v; ssq3[3] = fmaf(h3v, h3v, ssq3[3]);
        size_t pos = (tile0 + it) * 32 + pc;
        *(uint2*)(h3out + pos * 8 + kh * 4) =
            make_uint2(pack2(h0, h1v), pack2(h2, h3v));
        v0 = v1; v1 = nx;
    }
#pragma unroll
    for (int off = 1; off < 32; off <<= 1) {
#pragma unroll
        for (int r = 0; r < 4; r++) {
            sum3[r] += __shfl_xor(sum3[r], off);
            ssq3[r] += __shfl_xor(ssq3[r], off);
        }
    }
    __shared__ float red[4][16];
    if (pc == 0) {
#pragma unroll
        for (int r = 0; r < 4; r++) {
            red[wv][kh * 4 + r]     = sum3[r] * wf;
            red[wv][8 + kh * 4 + r] = ssq3[r] * wf;
        }
    }
    __syncthreads();
    if (tid < 16) {
        float v = red[0][tid] + red[1][tid] + red[2][tid] + red[3][tid];
        atomicAdd(stats3 + (blockIdx.x & 3) * 16 + tid, v);
    }
}

// --------------------------------------------------------------------------
// stats4 (VALU): block = 4 tiles (1024 pos); weighted moments of h4.
__global__ __launch_bounds__(256) void k_stats4(
        const unsigned short* __restrict__ h3,
        const float* __restrict__ stats3, const float* __restrict__ g3,
        const float* __restrict__ be3, const float* __restrict__ W4,
        const float* __restrict__ b4, float* __restrict__ stats4) {
    int tid = threadIdx.x;
    int og1 = tid & 1;

    float wtile[4];
#pragma unroll
    for (int p = 0; p < 4; p++) {
        int2 tc = tri_decode(blockIdx.x * 4 + p);
        wtile[p] = (tc.x == tc.y) ? 1.0f : 2.0f;
    }

    float sc[8], sh[8];
    bn8_inline(stats3, g3, be3, sc, sh);

    float w[4][8];
#pragma unroll
    for (int j = 0; j < 4; j++) {
        const float* wr = W4 + (og1 * 4 + j) * 8;
        float4 v0 = ld4(wr);
        float4 v1 = ld4(wr + 4);
        w[j][0] = v0.x; w[j][1] = v0.y; w[j][2] = v0.z; w[j][3] = v0.w;
        w[j][4] = v1.x; w[j][5] = v1.y; w[j][6] = v1.z; w[j][7] = v1.w;
    }
    float bi[4];
#pragma unroll
    for (int j = 0; j < 4; j++) bi[j] = b4[og1 * 4 + j];

    float sum[4] = {0.f, 0.f, 0.f, 0.f}, ssq[4] = {0.f, 0.f, 0.f, 0.f};

    size_t p0 = (size_t)blockIdx.x * 1024 + (tid >> 1);
    const uint4* src = (const uint4*)h3 + p0;

    auto proc = [&](uint4 v, float wf) {
        float a[8];
        a[0] = bflo(v.x); a[1] = bfhi(v.x); a[2] = bflo(v.y); a[3] = bfhi(v.y);
        a[4] = bflo(v.z); a[5] = bfhi(v.z); a[6] = bflo(v.w); a[7] = bfhi(v.w);
#pragma unroll
        for (int c = 0; c < 8; c++)
            a[c] = lrelu(fmaf(a[c], sc[c], sh[c]));
        float d[4] = {bi[0], bi[1], bi[2], bi[3]};
#pragma unroll
        for (int c = 0; c < 8; c++) {
#pragma unroll
            for (int j = 0; j < 4; j++)
                d[j] = fmaf(a[c], w[j][c], d[j]);
        }
#pragma unroll
        for (int j = 0; j < 4; j++) {
            float wd = wf * d[j];
            sum[j] += wd;
            ssq[j] = fmaf(wd, d[j], ssq[j]);
        }
    };

    uint4 vA = src[0];
    uint4 vB = src[128];
#pragma unroll 1
    for (int p = 0; p < 4; p++) {
        uint4 nA = vA, nB = vB;
        if (p < 3) {
            nA = src[(size_t)(2 * p + 2) * 128];
            nB = src[(size_t)(2 * p + 3) * 128];
        }
        proc(vA, wtile[p]);   // both chunks of pair p lie in tile p
        proc(vB, wtile[p]);
        vA = nA; vB = nB;
    }
#pragma unroll
    for (int off = 2; off < 64; off <<= 1) {
#pragma unroll
        for (int j = 0; j < 4; j++) {
            sum[j] += __shfl_xor(sum[j], off);
            ssq[j] += __shfl_xor(ssq[j], off);
        }
    }
    __shared__ float red[4][16];
    int wv = tid >> 6, lane = tid & 63;
    if (lane < 2) {
#pragma unroll
        for (int j = 0; j < 4; j++) {
            red[wv][og1 * 4 + j]     = sum[j];
            red[wv][8 + og1 * 4 + j] = ssq[j];
        }
    }
    __syncthreads();
    if (tid < 16) {
        float v = red[0][tid] + red[1][tid] + red[2][tid] + red[3][tid];
        atomicAdd(stats4 + (blockIdx.x & 3) * 16 + tid, v);
    }
}

// --------------------------------------------------------------------------
// last (VALU): block = 4 tiles; per tile decode (mt,nc) and write both the
// tile and its mirror (diag tiles: duplicate same-value stores, benign).
__global__ __launch_bounds__(256) void k_last(
        const unsigned short* __restrict__ h3,
        const float* __restrict__ stats3, const float* __restrict__ g3,
        const float* __restrict__ be3, const float* __restrict__ stats4,
        const float* __restrict__ g4, const float* __restrict__ be4,
        const float* __restrict__ W4, const float* __restrict__ b4,
        const float* __restrict__ W5, const float* __restrict__ b5,
        float* __restrict__ out) {
    int tid = threadIdx.x;

    size_t p0 = (size_t)blockIdx.x * 1024 + tid;
    const uint4* src = (const uint4*)h3 + p0;
    uint4 vv[4];
    vv[0] = src[0];
    vv[1] = src[256];
    vv[2] = src[512];
    vv[3] = src[768];

    float sc3[8], sh3[8];
    bn8_inline(stats3, g3, be3, sc3, sh3);

    float w4f[8][8], b4f[8], w5[8];
#pragma unroll
    for (int o = 0; o < 8; o++) {
        float S = stats4[o] + stats4[16 + o] + stats4[32 + o] + stats4[48 + o];
        float Q = stats4[8 + o] + stats4[24 + o] + stats4[40 + o] +
                  stats4[56 + o];
        float mu  = S * INV_M;
        float var = fmaf(-mu, mu, Q * INV_M);
        float s   = g4[o] * rsqrtf(var + EPS);
        float shv = fmaf(-mu, s, be4[o]);
        b4f[o] = fmaf(s, b4[o], shv);
        const float* wr = W4 + o * 8;
        float4 v0 = ld4(wr);
        float4 v1 = ld4(wr + 4);
        w4f[o][0] = s * v0.x; w4f[o][1] = s * v0.y;
        w4f[o][2] = s * v0.z; w4f[o][3] = s * v0.w;
        w4f[o][4] = s * v1.x; w4f[o][5] = s * v1.y;
        w4f[o][6] = s * v1.z; w4f[o][7] = s * v1.w;
        w5[o] = W5[o];
    }
    float b5v = b5[0];

    int nl = tid >> 4, ml = tid & 15;

#pragma unroll
    for (int it = 0; it < 4; it++) {
        uint4 va = vv[it];
        float a[8];
        a[0] = bflo(va.x); a[1] = bfhi(va.x); a[2] = bflo(va.y); a[3] = bfhi(va.y);
        a[4] = bflo(va.z); a[5] = bfhi(va.z); a[6] = bflo(va.w); a[7] = bfhi(va.w);
#pragma unroll
        for (int c = 0; c < 8; c++)
            a[c] = lrelu(fmaf(a[c], sc3[c], sh3[c]));
        float acc = b5v;
#pragma unroll
        for (int o = 0; o < 8; o++) {
            float h = b4f[o];
#pragma unroll
            for (int c = 0; c < 8; c++)
                h = fmaf(a[c], w4f[o][c], h);
            acc = fmaf(lrelu(h), w5[o], acc);
        }
        int2 tc = tri_decode(blockIdx.x * 4 + it);
        int gn = tc.y * 16 + nl;
        int gm = tc.x * 16 + ml;
        out[(size_t)gn * NPTS + gm] = acc;
        out[(size_t)gm * NPTS + gn] = acc;
    }
}

// --------------------------------------------------------------------------
extern "C" void kernel_launch(void* const* d_in, const int* in_sizes, int n_in,
                              void* d_out, int out_size, void* d_ws,
                              size_t ws_size, hipStream_t stream) {
    const float* x   = (const float*)d_in[0];
    const float* W1  = (const float*)d_in[1];
    const float* b1  = (const float*)d_in[2];
    const float* g1  = (const float*)d_in[3];
    const float* be1 = (const float*)d_in[4];
    const float* W2  = (const float*)d_in[5];
    const float* b2  = (const float*)d_in[6];
    const float* g2  = (const float*)d_in[7];
    const float* be2 = (const float*)d_in[8];
    const float* W3  = (const float*)d_in[9];
    const float* b3  = (const float*)d_in[10];
    const float* g3  = (const float*)d_in[11];
    const float* be3 = (const float*)d_in[12];
    const float* W4  = (const float*)d_in[13];
    const float* b4  = (const float*)d_in[14];
    const float* g4  = (const float*)d_in[15];
    const float* be4 = (const float*)d_in[16];
    const float* W5  = (const float*)d_in[17];
    const float* b5  = (const float*)d_in[18];

    float* ws     = (float*)d_ws;
    float* stats1 = ws + 0;     // 4 x 32
    float* raw2   = ws + 128;   // 4 x 32
    float* stats3 = ws + 256;   // 4 x 16
    float* stats4 = ws + 320;   // 4 x 16
    unsigned short* bufA = (unsigned short*)((char*)d_ws + 8192);
    unsigned short* bufB =
        (unsigned short*)((char*)d_ws + 8192 + (size_t)NTILES * 256 * 32);

    k_prep<<<2, 256, 0, stream>>>(ws);
    k_layer1<<<1164, 256, 0, stream>>>(x, W1, b1, bufA, stats1);
    k_stats2<<<1164, 256, 0, stream>>>(bufA, stats1, g1, be1, W2, raw2);
    k_fuse3<<<1164, 256, 0, stream>>>(bufA, bufB, stats1, g1, be1, W2,
                                      raw2, g2, be2, b2, W3, b3, stats3);
    k_stats4<<<1164, 256, 0, stream>>>(bufB, stats3, g3, be3, W4, b4, stats4);
    k_last<<<1164, 256, 0, stream>>>(bufB, stats3, g3, be3, stats4, g4, be4,
                                     W4, b4, W5, b5, (float*)d_out);
}

// Round 12
// 191.035 us; speedup vs baseline: 1.6839x; 1.0109x over previous
//
#include <hip/hip_runtime.h>
#include <stdint.h>

// ---------------------------------------------------------------------------
// AdjCompute R12 = R11 (193.1us, symmetry-halved triangle pipeline) with
// k_last's mirror store coalesced via LDS 16x16 transpose (stride-17 pad).
// R11 mirror was 16 rows x 16B segments per wave (4x store issue); now
// 4 x 64B per wave, same as the forward store.
//
// Pipeline (6 launches, grids 1164 = 4656 tiles / 4 waves):
//   k_prep    zero stats (384 floats)
//   k_layer1  MFMA 16x16x32: h1 tile -> bufA packed + stats1 (weighted)
//   k_stats2  MFMA 32x32x16: moments of d2 = W2*act1 (weighted, no write)
//   k_fuse3   MFMA 32x32x16 x2: act1 -> d2 -> act2 -> h3 -> bufB + stats3
//   k_stats4  VALU: stats of h4 (weighted, no write)
//   k_last    VALU: h3 -> out tile + LDS-transposed mirror tile (fp32)
//
// ws layout (floats), stats 4-replica:
//   [0..128)    stats1  4 x (sum16|ssq16)   stride 32
//   [128..256)  raw2    4 x (S16|Q16)       stride 32
//   [256..320)  stats3  4 x (sum8|ssq8)     stride 16
//   [320..384)  stats4  4 x (sum8|ssq8)     stride 16
//   byte 8192:            bufA h1: 4656*256*16 bf16 = 38,141,952 B
//   byte 8192+38141952:   bufB h3: 4656*256*8  bf16 = 19,070,976 B
//
// Tile t in [0,4656): (mt,nc), 0<=mt<=nc<96, row-major in mt.
// In-tile flat pos p = nl*16 + ml. Stats exact via off-diag x2 weights.
// MFMA layouts (HW-verified R4/R7): see R8 header.
// ---------------------------------------------------------------------------

#define NPTS 1536
#define NTILES 4656
static constexpr float FNN   = 2359296.0f;
static constexpr float EPS   = 1e-5f;
static constexpr float SLOPE = 0.01f;
static constexpr float INV_M = 1.0f / 2359296.0f;

typedef __attribute__((ext_vector_type(8)))  short bf16x8;
typedef __attribute__((ext_vector_type(4)))  float f32x4;
typedef __attribute__((ext_vector_type(16))) float f32x16;
union frag8 { int4 i; bf16x8 v; };

__device__ __forceinline__ float bflo(unsigned u) {
    return __builtin_bit_cast(float, u << 16);
}
__device__ __forceinline__ float bfhi(unsigned u) {
    return __builtin_bit_cast(float, u & 0xffff0000u);
}
__device__ __forceinline__ unsigned short f2bf(float f) {   // RNE
    unsigned u = __builtin_bit_cast(unsigned, f);
    u += 0x7fffu + ((u >> 16) & 1u);
    return (unsigned short)(u >> 16);
}
__device__ __forceinline__ unsigned pack2(float lo, float hi) {  // RNE pair
    return (unsigned)f2bf(lo) | ((unsigned)f2bf(hi) << 16);
}
__device__ __forceinline__ unsigned packtr(float lo, float hi) { // trunc
    unsigned a = __builtin_bit_cast(unsigned, lo);
    unsigned b = __builtin_bit_cast(unsigned, hi);
#if __has_builtin(__builtin_amdgcn_perm)
    return __builtin_amdgcn_perm(b, a, 0x07060302u);
#else
    return (a >> 16) | (b & 0xffff0000u);
#endif
}
__device__ __forceinline__ float lrelu(float t) {
    return fmaxf(t, t * SLOPE);
}
__device__ __forceinline__ float4 ld4(const float* p) {
    return *(const float4*)p;
}
__device__ __forceinline__ unsigned shflx32(unsigned v) {
    return (unsigned)__shfl_xor((int)v, 32);
}

// triangle tile decode: t -> (mt, nc), 0<=mt<=nc<96, row-major in mt.
// base(mt) = 96*mt - mt*(mt-1)/2.
__device__ __forceinline__ int2 tri_decode(int t) {
    float disc = 37249.0f - 8.0f * (float)t;    // 193^2 - 8t
    int mt = (int)((193.0f - sqrtf(disc)) * 0.5f);
    if (mt < 0) mt = 0;
    if (mt > 95) mt = 95;
    while (96 * (mt + 1) - ((mt + 1) * mt) / 2 <= t) mt++;
    while (96 * mt - (mt * (mt - 1)) / 2 > t) mt--;
    int nc = mt + (t - (96 * mt - (mt * (mt - 1)) / 2));
    return make_int2(mt, nc);
}

// bn over 8 channels from 4-replica 8ch stats (replica stride 16)
__device__ __forceinline__ void bn8_inline(
        const float* __restrict__ stats, const float* __restrict__ g,
        const float* __restrict__ be, float* sc, float* sh) {
#pragma unroll
    for (int c = 0; c < 8; c++) {
        float S = stats[c] + stats[16 + c] + stats[32 + c] + stats[48 + c];
        float Q = stats[8 + c] + stats[24 + c] + stats[40 + c] +
                  stats[56 + c];
        float mu  = S * INV_M;
        float var = fmaf(-mu, mu, Q * INV_M);
        float s   = g[c] * rsqrtf(var + EPS);
        sc[c] = s;
        sh[c] = fmaf(-mu, s, be[c]);
    }
}

// --------------------------------------------------------------------------
__global__ __launch_bounds__(256) void k_prep(float* __restrict__ ws) {
    int t = blockIdx.x * 256 + threadIdx.x;
    if (t < 384) ws[t] = 0.0f;
}

// --------------------------------------------------------------------------
// Layer 1: triangle tile gid -> h1 packed + weighted stats1.
// wave = 16 m (tile mt) x 16 n (chunk nc). MFMA A=W1, B=adj -> D[o][m].
__global__ __launch_bounds__(256) void k_layer1(
        const float* __restrict__ x, const float* __restrict__ W1,
        const float* __restrict__ b1, unsigned short* __restrict__ outb,
        float* __restrict__ stats) {
    int tid  = threadIdx.x;
    int lane = tid & 63;
    int wv   = tid >> 6;
    int gid  = blockIdx.x * 4 + wv;
    int2 tc  = tri_decode(gid);
    int mt   = tc.x;
    int nc   = tc.y;
    float wf = (mt == nc) ? 1.0f : 2.0f;
    int l15  = lane & 15;
    int quad = lane >> 4;
    int cb   = quad * 8;

    const float* wr = W1 + l15 * 64 + cb;
    float4 w0 = ld4(wr);
    float4 w1 = ld4(wr + 4);
    float4 w2 = ld4(wr + 32);
    float4 w3 = ld4(wr + 36);
    frag8 fb1, fb2;
    fb1.i = make_int4(pack2(w0.x, w0.y), pack2(w0.z, w0.w),
                      pack2(w1.x, w1.y), pack2(w1.z, w1.w));
    fb2.i = make_int4(pack2(w2.x, w2.y), pack2(w2.z, w2.w),
                      pack2(w3.x, w3.y), pack2(w3.z, w3.w));

    const float* xr = x + (mt * 16 + l15) * 64 + cb;
    float4 xa0 = ld4(xr);
    float4 xa1 = ld4(xr + 4);
    float4 xa2 = ld4(xr + 32);
    float4 xa3 = ld4(xr + 36);

    float4 b1v = ld4(b1 + quad * 4);
    float lsum[4] = {0.f, 0.f, 0.f, 0.f};
    float lssq[4] = {0.f, 0.f, 0.f, 0.f};

    int n0 = nc * 16;
    const float* xp = x + (size_t)n0 * 64 + cb;
    float4 uA0 = ld4(xp);
    float4 uA1 = ld4(xp + 4);
    float4 uA2 = ld4(xp + 32);
    float4 uA3 = ld4(xp + 36);
    const float* xq = x + (size_t)(n0 + 1) * 64 + cb;
    float4 uB0 = ld4(xq);
    float4 uB1 = ld4(xq + 4);
    float4 uB2 = ld4(xq + 32);
    float4 uB3 = ld4(xq + 36);

    auto body = [&](int i, float4& u0, float4& u1, float4& u2, float4& u3,
                    int pf) {
        frag8 fa1, fa2;
        fa1.i = make_int4(
            packtr(fabsf(xa0.x - u0.x), fabsf(xa0.y - u0.y)),
            packtr(fabsf(xa0.z - u0.z), fabsf(xa0.w - u0.w)),
            packtr(fabsf(xa1.x - u1.x), fabsf(xa1.y - u1.y)),
            packtr(fabsf(xa1.z - u1.z), fabsf(xa1.w - u1.w)));
        fa2.i = make_int4(
            packtr(fabsf(xa2.x - u2.x), fabsf(xa2.y - u2.y)),
            packtr(fabsf(xa2.z - u2.z), fabsf(xa2.w - u2.w)),
            packtr(fabsf(xa3.x - u3.x), fabsf(xa3.y - u3.y)),
            packtr(fabsf(xa3.z - u3.z), fabsf(xa3.w - u3.w)));
        const float* xf = x + (size_t)pf * 64 + cb;
        u0 = ld4(xf);
        u1 = ld4(xf + 4);
        u2 = ld4(xf + 32);
        u3 = ld4(xf + 36);
        f32x4 acc = {b1v.x, b1v.y, b1v.z, b1v.w};
        acc = __builtin_amdgcn_mfma_f32_16x16x32_bf16(fb1.v, fa1.v, acc, 0, 0, 0);
        acc = __builtin_amdgcn_mfma_f32_16x16x32_bf16(fb2.v, fa2.v, acc, 0, 0, 0);
        size_t pos = (size_t)gid * 256 + (size_t)i * 16 + l15;
#pragma unroll
        for (int r = 0; r < 4; r++) {
            lsum[r] += acc[r];
            lssq[r] = fmaf(acc[r], acc[r], lssq[r]);
        }
        *(uint2*)(outb + pos * 16 + quad * 4) =
            make_uint2(pack2(acc[0], acc[1]), pack2(acc[2], acc[3]));
    };

#pragma unroll 1
    for (int i = 0; i < 16; i += 2) {
        int pfA = n0 + ((i + 2 < 16) ? i + 2 : 15);
        int pfB = n0 + ((i + 3 < 16) ? i + 3 : 15);
        body(i,     uA0, uA1, uA2, uA3, pfA);
        body(i + 1, uB0, uB1, uB2, uB3, pfB);
    }

#pragma unroll
    for (int off = 1; off < 16; off <<= 1) {
#pragma unroll
        for (int r = 0; r < 4; r++) {
            lsum[r] += __shfl_xor(lsum[r], off);
            lssq[r] += __shfl_xor(lssq[r], off);
        }
    }
    __shared__ float red[4][32];
    if (l15 == 0) {
#pragma unroll
        for (int r = 0; r < 4; r++) {
            red[wv][quad * 4 + r]      = lsum[r] * wf;
            red[wv][16 + quad * 4 + r] = lssq[r] * wf;
        }
    }
    __syncthreads();
    if (tid < 32) {
        float v = red[0][tid] + red[1][tid] + red[2][tid] + red[3][tid];
        atomicAdd(stats + (blockIdx.x & 3) * 32 + tid, v);
    }
}

// --------------------------------------------------------------------------
// stats2 (32x32x16): tile gid = 8 chunks of 32 positions; weighted moments.
__global__ __launch_bounds__(256) void k_stats2(
        const unsigned short* __restrict__ h1,
        const float* __restrict__ stats1, const float* __restrict__ g1,
        const float* __restrict__ be1, const float* __restrict__ W2,
        float* __restrict__ raw2) {
    int tid  = threadIdx.x;
    int lane = tid & 63;
    int wv   = tid >> 6;
    int pc   = lane & 31;
    int kh   = lane >> 5;
    int gid  = blockIdx.x * 4 + wv;
    int2 tc  = tri_decode(gid);
    float wf = (tc.x == tc.y) ? 1.0f : 2.0f;

    float sc[8], sh[8];
#pragma unroll
    for (int j = 0; j < 8; j++) {
        int c = kh * 8 + j;
        float S = stats1[c] + stats1[32 + c] + stats1[64 + c] + stats1[96 + c];
        float Q = stats1[16 + c] + stats1[48 + c] + stats1[80 + c] +
                  stats1[112 + c];
        float mu  = S * INV_M;
        float var = fmaf(-mu, mu, Q * INV_M);
        float s   = g1[c] * rsqrtf(var + EPS);
        sc[j] = s;
        sh[j] = fmaf(-mu, s, be1[c]);
    }
    frag8 fw2; fw2.i = make_int4(0, 0, 0, 0);
    if (pc < 16) {
        const float* w = W2 + pc * 16 + kh * 8;
        float4 wa = ld4(w), wb = ld4(w + 4);
        fw2.i = make_int4(pack2(wa.x, wa.y), pack2(wa.z, wa.w),
                          pack2(wb.x, wb.y), pack2(wb.z, wb.w));
    }
    f32x16 z;
#pragma unroll
    for (int r = 0; r < 16; r++) z[r] = 0.0f;

    float sum[8], ssq[8];
#pragma unroll
    for (int r = 0; r < 8; r++) { sum[r] = 0.f; ssq[r] = 0.f; }

    size_t tile0 = (size_t)gid * 8;
    const unsigned short* ptr = h1 + (tile0 * 32 + pc) * 16 + kh * 8;

    auto proc = [&](uint4 v) {
        float a0 = bflo(v.x), a1 = bfhi(v.x);
        float a2 = bflo(v.y), a3 = bfhi(v.y);
        float a4 = bflo(v.z), a5 = bfhi(v.z);
        float a6 = bflo(v.w), a7 = bfhi(v.w);
        a0 = lrelu(fmaf(a0, sc[0], sh[0]));
        a1 = lrelu(fmaf(a1, sc[1], sh[1]));
        a2 = lrelu(fmaf(a2, sc[2], sh[2]));
        a3 = lrelu(fmaf(a3, sc[3], sh[3]));
        a4 = lrelu(fmaf(a4, sc[4], sh[4]));
        a5 = lrelu(fmaf(a5, sc[5], sh[5]));
        a6 = lrelu(fmaf(a6, sc[6], sh[6]));
        a7 = lrelu(fmaf(a7, sc[7], sh[7]));
        frag8 fb;
        fb.i = make_int4(packtr(a0, a1), packtr(a2, a3),
                         packtr(a4, a5), packtr(a6, a7));
        f32x16 d = __builtin_amdgcn_mfma_f32_32x32x16_bf16(fw2.v, fb.v, z, 0, 0, 0);
#pragma unroll
        for (int r = 0; r < 8; r++) {
            sum[r] += d[r];
            ssq[r] = fmaf(d[r], d[r], ssq[r]);
        }
    };

    uint4 vA = *(const uint4*)(ptr);
    uint4 vB = *(const uint4*)(ptr + 512);
#pragma unroll 1
    for (int p = 0; p < 4; p++) {
        uint4 nA = vA, nB = vB;
        if (p < 3) {
            nA = *(const uint4*)(ptr + (size_t)(2 * p + 2) * 512);
            nB = *(const uint4*)(ptr + (size_t)(2 * p + 3) * 512);
        }
        proc(vA);
        proc(vB);
        vA = nA; vB = nB;
    }

#pragma unroll
    for (int off = 1; off < 32; off <<= 1) {
#pragma unroll
        for (int r = 0; r < 8; r++) {
            sum[r] += __shfl_xor(sum[r], off);
            ssq[r] += __shfl_xor(ssq[r], off);
        }
    }
    __shared__ float red[4][32];
    if (pc == 0) {
#pragma unroll
        for (int r = 0; r < 8; r++) {
            int o = (r & 3) + 8 * (r >> 2) + 4 * kh;
            red[wv][o]      = sum[r] * wf;
            red[wv][16 + o] = ssq[r] * wf;
        }
    }
    __syncthreads();
    if (tid < 32) {
        float v = red[0][tid] + red[1][tid] + red[2][tid] + red[3][tid];
        atomicAdd(raw2 + (blockIdx.x & 3) * 32 + tid, v);
    }
}

// --------------------------------------------------------------------------
// fuse3 (32x32x16 x2): tile gid; weighted stats3; h3 packed.
__global__ __launch_bounds__(256) void k_fuse3(
        const unsigned short* __restrict__ h1,
        unsigned short* __restrict__ h3out,
        const float* __restrict__ stats1, const float* __restrict__ g1,
        const float* __restrict__ be1, const float* __restrict__ W2,
        const float* __restrict__ raw2, const float* __restrict__ g2,
        const float* __restrict__ be2, const float* __restrict__ b2,
        const float* __restrict__ W3, const float* __restrict__ b3,
        float* __restrict__ stats3) {
    int tid  = threadIdx.x;
    int lane = tid & 63;
    int wv   = tid >> 6;
    int pc   = lane & 31;
    int kh   = lane >> 5;
    int gid  = blockIdx.x * 4 + wv;
    int2 tc  = tri_decode(gid);
    float wf = (tc.x == tc.y) ? 1.0f : 2.0f;

    float sc[8], sh[8];
#pragma unroll
    for (int j = 0; j < 8; j++) {
        int c = kh * 8 + j;
        float S = stats1[c] + stats1[32 + c] + stats1[64 + c] + stats1[96 + c];
        float Q = stats1[16 + c] + stats1[48 + c] + stats1[80 + c] +
                  stats1[112 + c];
        float mu  = S * INV_M;
        float var = fmaf(-mu, mu, Q * INV_M);
        float s   = g1[c] * rsqrtf(var + EPS);
        sc[j] = s;
        sh[j] = fmaf(-mu, s, be1[c]);
    }
    float sc2[8], sh2[8];
#pragma unroll
    for (int r = 0; r < 8; r++) {
        int c = (r & 3) + 8 * (r >> 2) + 4 * kh;
        float S = raw2[c] + raw2[32 + c] + raw2[64 + c] + raw2[96 + c];
        float Q = raw2[16 + c] + raw2[48 + c] + raw2[80 + c] + raw2[112 + c];
        float bc = b2[c];
        float sm = S + FNN * bc;
        float sq = Q + 2.0f * bc * S + FNN * bc * bc;
        float mu  = sm * INV_M;
        float var = fmaf(-mu, mu, sq * INV_M);
        float s   = g2[c] * rsqrtf(var + EPS);
        float shv = fmaf(-mu, s, be2[c]);
        sc2[r] = s;
        sh2[r] = fmaf(s, bc, shv);
    }
    frag8 fw2; fw2.i = make_int4(0, 0, 0, 0);
    if (pc < 16) {
        const float* w = W2 + pc * 16 + kh * 8;
        float4 wa = ld4(w), wb = ld4(w + 4);
        fw2.i = make_int4(pack2(wa.x, wa.y), pack2(wa.z, wa.w),
                          pack2(wb.x, wb.y), pack2(wb.z, wb.w));
    }
    frag8 fw3; fw3.i = make_int4(0, 0, 0, 0);
    if (pc < 8) {
        const float* w = W3 + pc * 16 + kh * 8;
        float4 wa = ld4(w), wb = ld4(w + 4);
        fw3.i = make_int4(pack2(wa.x, wa.y), pack2(wa.z, wa.w),
                          pack2(wb.x, wb.y), pack2(wb.z, wb.w));
    }
    float b3r[4];
#pragma unroll
    for (int r = 0; r < 4; r++) b3r[r] = b3[kh * 4 + r];

    f32x16 z;
#pragma unroll
    for (int r = 0; r < 16; r++) z[r] = 0.0f;

    float sum3[4] = {0.f, 0.f, 0.f, 0.f}, ssq3[4] = {0.f, 0.f, 0.f, 0.f};

    size_t tile0 = (size_t)gid * 8;
    const unsigned short* ptr = h1 + (tile0 * 32 + pc) * 16 + kh * 8;

    uint4 v0 = *(const uint4*)(ptr);
    uint4 v1 = *(const uint4*)(ptr + 512);
#pragma unroll 1
    for (int it = 0; it < 8; it++) {
        uint4 nx = v0;
        if (it + 2 < 8)
            nx = *(const uint4*)(ptr + (size_t)(it + 2) * 512);
        float a0 = bflo(v0.x), a1 = bfhi(v0.x);
        float a2 = bflo(v0.y), a3 = bfhi(v0.y);
        float a4 = bflo(v0.z), a5 = bfhi(v0.z);
        float a6 = bflo(v0.w), a7 = bfhi(v0.w);
        a0 = lrelu(fmaf(a0, sc[0], sh[0]));
        a1 = lrelu(fmaf(a1, sc[1], sh[1]));
        a2 = lrelu(fmaf(a2, sc[2], sh[2]));
        a3 = lrelu(fmaf(a3, sc[3], sh[3]));
        a4 = lrelu(fmaf(a4, sc[4], sh[4]));
        a5 = lrelu(fmaf(a5, sc[5], sh[5]));
        a6 = lrelu(fmaf(a6, sc[6], sh[6]));
        a7 = lrelu(fmaf(a7, sc[7], sh[7]));
        frag8 fb;
        fb.i = make_int4(packtr(a0, a1), packtr(a2, a3),
                         packtr(a4, a5), packtr(a6, a7));
        f32x16 d = __builtin_amdgcn_mfma_f32_32x32x16_bf16(fw2.v, fb.v, z, 0, 0, 0);
        float t0 = lrelu(fmaf(d[0], sc2[0], sh2[0]));
        float t1 = lrelu(fmaf(d[1], sc2[1], sh2[1]));
        float t2 = lrelu(fmaf(d[2], sc2[2], sh2[2]));
        float t3 = lrelu(fmaf(d[3], sc2[3], sh2[3]));
        float t4 = lrelu(fmaf(d[4], sc2[4], sh2[4]));
        float t5 = lrelu(fmaf(d[5], sc2[5], sh2[5]));
        float t6 = lrelu(fmaf(d[6], sc2[6], sh2[6]));
        float t7 = lrelu(fmaf(d[7], sc2[7], sh2[7]));
        unsigned w0 = packtr(t0, t1), w1 = packtr(t2, t3);
        unsigned w2 = packtr(t4, t5), w3 = packtr(t6, t7);
        unsigned p0 = kh ? w0 : w2;
        unsigned p1 = kh ? w1 : w3;
        unsigned q0 = shflx32(p0);
        unsigned q1 = shflx32(p1);
        frag8 fb2;
        fb2.i = make_int4(kh ? q0 : w0, kh ? q1 : w1,
                          kh ? w2 : q0, kh ? w3 : q1);
        f32x16 d2 = __builtin_amdgcn_mfma_f32_32x32x16_bf16(fw3.v, fb2.v, z, 0, 0, 0);
        float h0 = d2[0] + b3r[0];
        float h1v = d2[1] + b3r[1];
        float h2 = d2[2] + b3r[2];
        float h3v = d2[3] + b3r[3];
        sum3[0] += h0;  ssq3[0] = fmaf(h0, h0, ssq3[0]);
        sum3[1] += h1v; ssq3[1] = fmaf(h1v, h1v, ssq3[1]);
        sum3[2] += h2;  ssq3[2] = fmaf(h2, h2, ssq3[2]);
        sum3[3] += h3v; ssq3[3] = fmaf(h3v, h3v, ssq3[3]);
        size_t pos = (tile0 + it) * 32 + pc;
        *(uint2*)(h3out + pos * 8 + kh * 4) =
            make_uint2(pack2(h0, h1v), pack2(h2, h3v));
        v0 = v1; v1 = nx;
    }
#pragma unroll
    for (int off = 1; off < 32; off <<= 1) {
#pragma unroll
        for (int r = 0; r < 4; r++) {
            sum3[r] += __shfl_xor(sum3[r], off);
            ssq3[r] += __shfl_xor(ssq3[r], off);
        }
    }
    __shared__ float red[4][16];
    if (pc == 0) {
#pragma unroll
        for (int r = 0; r < 4; r++) {
            red[wv][kh * 4 + r]     = sum3[r] * wf;
            red[wv][8 + kh * 4 + r] = ssq3[r] * wf;
        }
    }
    __syncthreads();
    if (tid < 16) {
        float v = red[0][tid] + red[1][tid] + red[2][tid] + red[3][tid];
        atomicAdd(stats3 + (blockIdx.x & 3) * 16 + tid, v);
    }
}

// --------------------------------------------------------------------------
// stats4 (VALU): block = 4 tiles (1024 pos); weighted moments of h4.
__global__ __launch_bounds__(256) void k_stats4(
        const unsigned short* __restrict__ h3,
        const float* __restrict__ stats3, const float* __restrict__ g3,
        const float* __restrict__ be3, const float* __restrict__ W4,
        const float* __restrict__ b4, float* __restrict__ stats4) {
    int tid = threadIdx.x;
    int og1 = tid & 1;

    float wtile[4];
#pragma unroll
    for (int p = 0; p < 4; p++) {
        int2 tc = tri_decode(blockIdx.x * 4 + p);
        wtile[p] = (tc.x == tc.y) ? 1.0f : 2.0f;
    }

    float sc[8], sh[8];
    bn8_inline(stats3, g3, be3, sc, sh);

    float w[4][8];
#pragma unroll
    for (int j = 0; j < 4; j++) {
        const float* wr = W4 + (og1 * 4 + j) * 8;
        float4 v0 = ld4(wr);
        float4 v1 = ld4(wr + 4);
        w[j][0] = v0.x; w[j][1] = v0.y; w[j][2] = v0.z; w[j][3] = v0.w;
        w[j][4] = v1.x; w[j][5] = v1.y; w[j][6] = v1.z; w[j][7] = v1.w;
    }
    float bi[4];
#pragma unroll
    for (int j = 0; j < 4; j++) bi[j] = b4[og1 * 4 + j];

    float sum[4] = {0.f, 0.f, 0.f, 0.f}, ssq[4] = {0.f, 0.f, 0.f, 0.f};

    size_t p0 = (size_t)blockIdx.x * 1024 + (tid >> 1);
    const uint4* src = (const uint4*)h3 + p0;

    auto proc = [&](uint4 v, float wf) {
        float a[8];
        a[0] = bflo(v.x); a[1] = bfhi(v.x); a[2] = bflo(v.y); a[3] = bfhi(v.y);
        a[4] = bflo(v.z); a[5] = bfhi(v.z); a[6] = bflo(v.w); a[7] = bfhi(v.w);
#pragma unroll
        for (int c = 0; c < 8; c++)
            a[c] = lrelu(fmaf(a[c], sc[c], sh[c]));
        float d[4] = {bi[0], bi[1], bi[2], bi[3]};
#pragma unroll
        for (int c = 0; c < 8; c++) {
#pragma unroll
            for (int j = 0; j < 4; j++)
                d[j] = fmaf(a[c], w[j][c], d[j]);
        }
#pragma unroll
        for (int j = 0; j < 4; j++) {
            float wd = wf * d[j];
            sum[j] += wd;
            ssq[j] = fmaf(wd, d[j], ssq[j]);
        }
    };

    uint4 vA = src[0];
    uint4 vB = src[128];
#pragma unroll 1
    for (int p = 0; p < 4; p++) {
        uint4 nA = vA, nB = vB;
        if (p < 3) {
            nA = src[(size_t)(2 * p + 2) * 128];
            nB = src[(size_t)(2 * p + 3) * 128];
        }
        proc(vA, wtile[p]);   // both chunks of pair p lie in tile p
        proc(vB, wtile[p]);
        vA = nA; vB = nB;
    }
#pragma unroll
    for (int off = 2; off < 64; off <<= 1) {
#pragma unroll
        for (int j = 0; j < 4; j++) {
            sum[j] += __shfl_xor(sum[j], off);
            ssq[j] += __shfl_xor(ssq[j], off);
        }
    }
    __shared__ float red[4][16];
    int wv = tid >> 6, lane = tid & 63;
    if (lane < 2) {
#pragma unroll
        for (int j = 0; j < 4; j++) {
            red[wv][og1 * 4 + j]     = sum[j];
            red[wv][8 + og1 * 4 + j] = ssq[j];
        }
    }
    __syncthreads();
    if (tid < 16) {
        float v = red[0][tid] + red[1][tid] + red[2][tid] + red[3][tid];
        atomicAdd(stats4 + (blockIdx.x & 3) * 16 + tid, v);
    }
}

// --------------------------------------------------------------------------
// last (VALU): block = 4 tiles. Forward store coalesced; mirror store made
// coalesced via per-tile LDS 16x16 transpose (stride 17 -> <=2-way alias,
// free per m136). Diag tiles: duplicate stores carry bit-identical values.
__global__ __launch_bounds__(256) void k_last(
        const unsigned short* __restrict__ h3,
        const float* __restrict__ stats3, const float* __restrict__ g3,
        const float* __restrict__ be3, const float* __restrict__ stats4,
        const float* __restrict__ g4, const float* __restrict__ be4,
        const float* __restrict__ W4, const float* __restrict__ b4,
        const float* __restrict__ W5, const float* __restrict__ b5,
        float* __restrict__ out) {
    int tid = threadIdx.x;

    size_t p0 = (size_t)blockIdx.x * 1024 + tid;
    const uint4* src = (const uint4*)h3 + p0;
    uint4 vv[4];
    vv[0] = src[0];
    vv[1] = src[256];
    vv[2] = src[512];
    vv[3] = src[768];

    float sc3[8], sh3[8];
    bn8_inline(stats3, g3, be3, sc3, sh3);

    float w4f[8][8], b4f[8], w5[8];
#pragma unroll
    for (int o = 0; o < 8; o++) {
        float S = stats4[o] + stats4[16 + o] + stats4[32 + o] + stats4[48 + o];
        float Q = stats4[8 + o] + stats4[24 + o] + stats4[40 + o] +
                  stats4[56 + o];
        float mu  = S * INV_M;
        float var = fmaf(-mu, mu, Q * INV_M);
        float s   = g4[o] * rsqrtf(var + EPS);
        float shv = fmaf(-mu, s, be4[o]);
        b4f[o] = fmaf(s, b4[o], shv);
        const float* wr = W4 + o * 8;
        float4 v0 = ld4(wr);
        float4 v1 = ld4(wr + 4);
        w4f[o][0] = s * v0.x; w4f[o][1] = s * v0.y;
        w4f[o][2] = s * v0.z; w4f[o][3] = s * v0.w;
        w4f[o][4] = s * v1.x; w4f[o][5] = s * v1.y;
        w4f[o][6] = s * v1.z; w4f[o][7] = s * v1.w;
        w5[o] = W5[o];
    }
    float b5v = b5[0];

    int nl = tid >> 4, ml = tid & 15;
    int2 tcs[4];
#pragma unroll
    for (int it = 0; it < 4; it++)
        tcs[it] = tri_decode(blockIdx.x * 4 + it);

    __shared__ float T[4][272];   // [tile][nl*17+ml]

#pragma unroll
    for (int it = 0; it < 4; it++) {
        uint4 va = vv[it];
        float a[8];
        a[0] = bflo(va.x); a[1] = bfhi(va.x); a[2] = bflo(va.y); a[3] = bfhi(va.y);
        a[4] = bflo(va.z); a[5] = bfhi(va.z); a[6] = bflo(va.w); a[7] = bfhi(va.w);
#pragma unroll
        for (int c = 0; c < 8; c++)
            a[c] = lrelu(fmaf(a[c], sc3[c], sh3[c]));
        float acc = b5v;
#pragma unroll
        for (int o = 0; o < 8; o++) {
            float h = b4f[o];
#pragma unroll
            for (int c = 0; c < 8; c++)
                h = fmaf(a[c], w4f[o][c], h);
            acc = fmaf(lrelu(h), w5[o], acc);
        }
        int gn = tcs[it].y * 16 + nl;
        int gm = tcs[it].x * 16 + ml;
        out[(size_t)gn * NPTS + gm] = acc;     // forward: coalesced
        T[it][nl * 17 + ml] = acc;
    }
    __syncthreads();
#pragma unroll
    for (int it = 0; it < 4; it++) {
        // value of original lane (nl_o = ml, ml_o = nl)
        float mv = T[it][ml * 17 + nl];
        // mirror: row = mt*16 + nl, col = nc*16 + ml -> coalesced over ml
        out[(size_t)(tcs[it].x * 16 + nl) * NPTS + tcs[it].y * 16 + ml] = mv;
    }
}

// --------------------------------------------------------------------------
extern "C" void kernel_launch(void* const* d_in, const int* in_sizes, int n_in,
                              void* d_out, int out_size, void* d_ws,
                              size_t ws_size, hipStream_t stream) {
    const float* x   = (const float*)d_in[0];
    const float* W1  = (const float*)d_in[1];
    const float* b1  = (const float*)d_in[2];
    const float* g1  = (const float*)d_in[3];
    const float* be1 = (const float*)d_in[4];
    const float* W2  = (const float*)d_in[5];
    const float* b2  = (const float*)d_in[6];
    const float* g2  = (const float*)d_in[7];
    const float* be2 = (const float*)d_in[8];
    const float* W3  = (const float*)d_in[9];
    const float* b3  = (const float*)d_in[10];
    const float* g3  = (const float*)d_in[11];
    const float* be3 = (const float*)d_in[12];
    const float* W4  = (const float*)d_in[13];
    const float* b4  = (const float*)d_in[14];
    const float* g4  = (const float*)d_in[15];
    const float* be4 = (const float*)d_in[16];
    const float* W5  = (const float*)d_in[17];
    const float* b5  = (const float*)d_in[18];

    float* ws     = (float*)d_ws;
    float* stats1 = ws + 0;     // 4 x 32
    float* raw2   = ws + 128;   // 4 x 32
    float* stats3 = ws + 256;   // 4 x 16
    float* stats4 = ws + 320;   // 4 x 16
    unsigned short* bufA = (unsigned short*)((char*)d_ws + 8192);
    unsigned short* bufB =
        (unsigned short*)((char*)d_ws + 8192 + (size_t)NTILES * 256 * 32);

    k_prep<<<2, 256, 0, stream>>>(ws);
    k_layer1<<<1164, 256, 0, stream>>>(x, W1, b1, bufA, stats1);
    k_stats2<<<1164, 256, 0, stream>>>(bufA, stats1, g1, be1, W2, raw2);
    k_fuse3<<<1164, 256, 0, stream>>>(bufA, bufB, stats1, g1, be1, W2,
                                      raw2, g2, be2, b2, W3, b3, stats3);
    k_stats4<<<1164, 256, 0, stream>>>(bufB, stats3, g3, be3, W4, b4, stats4);
    k_last<<<1164, 256, 0, stream>>>(bufB, stats3, g3, be3, stats4, g4, be4,
                                     W4, b4, W5, b5, (float*)d_out);
}